// Round 9
// baseline (50.079 us; speedup 1.0000x reference)
//
#include <hip/hip_runtime.h>

#define NB 64
#define KP1 129
#define DD 128
#define NROWS 50000
#define EPSF 1e-6f
#define E128F (128.0f*EPSF*EPSF)
#define OUT_SIDE (NB*NB*KP1)            // 528384 per side
#define L2E_T 28.853900817779268f       // log2(e)/T, T=0.05
#define RSQRT_D 0.08838834764831845f    // 1/sqrt(128)
#define TLP 65                          // padded stride of the LDS result tile
#define NF4PB 6250                      // 1,600,000 float4 per bank / 256 threads

__device__ __forceinline__ float4 ldf4(const float* p) { return *(const float4*)p; }

// ---------------- pure bank copy: 1 float4 per thread, no LDS, no loop ----------------
__global__ __launch_bounds__(256) void k_copy(
    const float* __restrict__ mem1, const float* __restrict__ mem2,
    float* __restrict__ dout)
{
    const int bid = blockIdx.x;
    const int bank = (bid >= NF4PB);
    const size_t i = (size_t)(bank ? bid - NF4PB : bid) * 256 + threadIdx.x;
    const float4* src = (const float4*)(bank ? mem2 : mem1);
    float4* dst = (float4*)(dout + (size_t)2*OUT_SIDE + (size_t)bank*NROWS*DD);
    dst[i] = src[i];
}

// ---------------- gram GEMM + epilogue: 258 blocks, full-K staging ----------------
// out_raw[a,b,k] = exp(( (w·u) - (w·an) - (u·an) + ||an||^2
//                 + eps*(Sw+Su-2San) + 128eps^2 ) / (||w-an+eps||*||u-an+eps||) / T)
__global__ __launch_bounds__(256, 2) void k_gemm(
    const float* __restrict__ v1, const float* __restrict__ v2,
    const float* __restrict__ mem1, const float* __restrict__ mem2,
    const int* __restrict__ y, const int* __restrict__ idx,
    float* __restrict__ dout, double* __restrict__ sums)
{
    __shared__ float A2[128*64];          // [k][r] w-rows, transposed; epilogue Tl overlay
    __shared__ float B2[128*64];          // [k][c] anchor rows, transposed
    __shared__ float dotwul[64], swl[64], wql[64];
    __shared__ float sanl[64], anql[64], g1l0[64], g1l1[64];
    __shared__ int   lidxl[64], yl[64];
    __shared__ float sul[2], usql[2];
    __shared__ double lsumd[4];

    const int bid = blockIdx.x;
    const int tid = threadIdx.x;
    const int s  = bid / 129;             // side: 0 -> (v1, mem2), 1 -> (v2, mem1)
    const int rb = bid % 129;
    const float* v   = s ? v2 : v1;
    const float* mem = s ? mem1 : mem2;
    const int a0 = (rb*64) / 129;
    const int a1 = (rb*64 + 63) / 129;    // a0 or a0+1
    const int kst0 = rb*64 - a0*129;      // k-start of the a0 run
    const int L0   = min(64, 129 - kst0); // rows belonging to a0
    const int L1   = 64 - L0;             // rows belonging to a1 (may be 0)

    const int r  = tid >> 2;              // 0..63: A-row AND B-col index
    const int ch = tid & 3;               // 4 chunk-threads per row, adjacent lanes

    const int g    = rb*64 + r;
    const int ag   = g / 129;
    const int mrow = idx[g];
    const int crow = y[r];
    if (ch == 0) { lidxl[r] = mrow; yl[r] = crow; }

    const float* wrow = mem + (size_t)mrow*DD;
    const float* urow = v   + (size_t)ag*DD;
    const float* brow = mem + (size_t)crow*DD;
    const float* u0p  = v   + (size_t)a0*DD;
    const float* u1p  = v   + (size_t)a1*DD;

    // ---- u stats: Su, ||u||^2 for a0, a1 (8 threads, shuffle-reduced) ----
    if (tid < 8) {
        const int au = tid & 1, c2 = tid >> 1;
        const float* up = au ? u1p : u0p;
        float ps = 0.f, pq = 0.f;
        #pragma unroll
        for (int i = 0; i < 8; ++i) {
            float4 uu = ldf4(up + c2*32 + i*4);
            ps += (uu.x + uu.y) + (uu.z + uu.w);
            pq = fmaf(uu.x,uu.x, fmaf(uu.y,uu.y, fmaf(uu.z,uu.z, fmaf(uu.w,uu.w, pq))));
        }
        ps += __shfl_xor(ps, 2, 64); pq += __shfl_xor(pq, 2, 64);
        ps += __shfl_xor(ps, 4, 64); pq += __shfl_xor(pq, 4, 64);
        if (tid < 2) { sul[au] = ps; usql[au] = pq; }
    }

    // ---- full-K staging + stats (one deep load pipeline, single barrier) ----
    float pd=0.f, ps=0.f, pq=0.f;         // A-row stats: w·u, Sw, Sww
    float pn=0.f, pqB=0.f, p0=0.f, p1=0.f;// B-col stats: San, Sanan, an·u0, an·u1
    #pragma unroll
    for (int i = 0; i < 8; ++i) {
        const int d = ch*32 + i*4;
        float4 w  = ldf4(wrow + d);
        float4 uu = ldf4(urow + d);
        A2[(d+0)*64 + r] = w.x;
        A2[(d+1)*64 + r] = w.y;
        A2[(d+2)*64 + r] = w.z;
        A2[(d+3)*64 + r] = w.w;
        pd = fmaf(w.x,uu.x, fmaf(w.y,uu.y, fmaf(w.z,uu.z, fmaf(w.w,uu.w, pd))));
        ps += (w.x + w.y) + (w.z + w.w);
        pq = fmaf(w.x,w.x, fmaf(w.y,w.y, fmaf(w.z,w.z, fmaf(w.w,w.w, pq))));
    }
    #pragma unroll
    for (int i = 0; i < 8; ++i) {
        const int d = ch*32 + i*4;
        float4 an = ldf4(brow + d);
        float4 q0 = ldf4(u0p  + d);
        float4 q1 = ldf4(u1p  + d);
        B2[(d+0)*64 + r] = an.x;
        B2[(d+1)*64 + r] = an.y;
        B2[(d+2)*64 + r] = an.z;
        B2[(d+3)*64 + r] = an.w;
        pn += (an.x + an.y) + (an.z + an.w);
        pqB = fmaf(an.x,an.x, fmaf(an.y,an.y, fmaf(an.z,an.z, fmaf(an.w,an.w, pqB))));
        p0 = fmaf(an.x,q0.x, fmaf(an.y,q0.y, fmaf(an.z,q0.z, fmaf(an.w,q0.w, p0))));
        p1 = fmaf(an.x,q1.x, fmaf(an.y,q1.y, fmaf(an.z,q1.z, fmaf(an.w,q1.w, p1))));
    }
    __syncthreads();

    // ---- GEMM: 64x64 tile, thread tile 4r x 4c, K=128 straight through ----
    const int r0 = (tid >> 4) << 2;
    const int c0 = (tid & 15) << 2;
    float acc[4][4] = {{0.f,0.f,0.f,0.f},{0.f,0.f,0.f,0.f},{0.f,0.f,0.f,0.f},{0.f,0.f,0.f,0.f}};
    #pragma unroll 8
    for (int kk = 0; kk < 128; ++kk) {
        float4 av = *(float4*)&A2[kk*64 + r0];
        float4 bv = *(float4*)&B2[kk*64 + c0];
        acc[0][0]=fmaf(av.x,bv.x,acc[0][0]); acc[0][1]=fmaf(av.x,bv.y,acc[0][1]);
        acc[0][2]=fmaf(av.x,bv.z,acc[0][2]); acc[0][3]=fmaf(av.x,bv.w,acc[0][3]);
        acc[1][0]=fmaf(av.y,bv.x,acc[1][0]); acc[1][1]=fmaf(av.y,bv.y,acc[1][1]);
        acc[1][2]=fmaf(av.y,bv.z,acc[1][2]); acc[1][3]=fmaf(av.y,bv.w,acc[1][3]);
        acc[2][0]=fmaf(av.z,bv.x,acc[2][0]); acc[2][1]=fmaf(av.z,bv.y,acc[2][1]);
        acc[2][2]=fmaf(av.z,bv.z,acc[2][2]); acc[2][3]=fmaf(av.z,bv.w,acc[2][3]);
        acc[3][0]=fmaf(av.w,bv.x,acc[3][0]); acc[3][1]=fmaf(av.w,bv.y,acc[3][1]);
        acc[3][2]=fmaf(av.w,bv.z,acc[3][2]); acc[3][3]=fmaf(av.w,bv.w,acc[3][3]);
    }

    // ---- reduce stats across the 4 chunk-lanes (adjacent), publish to LDS ----
    pd += __shfl_xor(pd, 1, 64); ps += __shfl_xor(ps, 1, 64); pq += __shfl_xor(pq, 1, 64);
    pn += __shfl_xor(pn, 1, 64); pqB += __shfl_xor(pqB, 1, 64);
    p0 += __shfl_xor(p0, 1, 64); p1 += __shfl_xor(p1, 1, 64);
    pd += __shfl_xor(pd, 2, 64); ps += __shfl_xor(ps, 2, 64); pq += __shfl_xor(pq, 2, 64);
    pn += __shfl_xor(pn, 2, 64); pqB += __shfl_xor(pqB, 2, 64);
    p0 += __shfl_xor(p0, 2, 64); p1 += __shfl_xor(p1, 2, 64);
    if (ch == 0) {
        dotwul[r] = pd; swl[r] = ps; wql[r] = pq;
        sanl[r] = pn; anql[r] = pqB; g1l0[r] = p0; g1l1[r] = p1;
    }
    __syncthreads();

    // ---- epilogue: assemble + exp into LDS tile Tl[g][b] (stride 65) ----
    float* Tl = A2;                       // GEMM reads done (barrier above)
    float dwr[4], swr[4], wqr[4];
    int   idr[4], aur[4];
    #pragma unroll
    for (int i = 0; i < 4; ++i) {
        const int rr = r0 + i;
        dwr[i] = dotwul[rr]; swr[i] = swl[rr]; wqr[i] = wql[rr];
        idr[i] = lidxl[rr];  aur[i] = (rr >= L0);
    }
    double zacc = 0.0;
    #pragma unroll
    for (int j = 0; j < 4; ++j) {
        const int b = c0 + j;
        const float sanb = sanl[b], anqb = anql[b];
        const int yb = yl[b];
        const float g1v[2] = { g1l0[b], g1l1[b] };
        float rdu[2], vem[2];
        #pragma unroll
        for (int au = 0; au < 2; ++au) {
            const float du2 = usql[au] - 2.f*g1v[au] + anqb
                            + 2.f*EPSF*(sul[au] - sanb) + E128F;
            rdu[au] = rsqrtf(fmaxf(du2, 1e-20f));
            vem[au] = exp2f((sul[au] - sanb + 128.f*EPSF) * rdu[au] * (RSQRT_D*L2E_T));
        }
        #pragma unroll
        for (int i = 0; i < 4; ++i) {
            const int au = aur[i];
            const float C2 = acc[i][j];
            const float N = dwr[i] - C2 - g1v[au] + anqb
                          + EPSF*(swr[i] + sul[au] - 2.f*sanb) + E128F;
            const float dw2 = wqr[i] - 2.f*C2 + anqb
                            + 2.f*EPSF*(swr[i] - sanb) + E128F;
            float val = exp2f(N * rsqrtf(fmaxf(dw2, 1e-20f)) * rdu[au] * L2E_T);
            if (idr[i] == yb) val = vem[au];
            Tl[(r0 + i)*TLP + b] = val;
            zacc += (double)val;
        }
    }
    // in-wave f64 reduce of zacc; lane 0 of each wave -> lsumd
    #pragma unroll
    for (int m = 1; m < 64; m <<= 1) zacc += __shfl_xor(zacc, m, 64);
    if ((tid & 63) == 0) lsumd[tid >> 6] = zacc;
    __syncthreads();

    // ---- coalesced out-write: lanes span k within an out-row ----
    {
        const int lane = tid & 63;
        const int w    = tid >> 6;
        for (int rr = w*32; rr < w*32 + 32; ++rr) {
            const int asel = rr >> 6;
            const int b    = rr & 63;
            const int aa   = asel ? a1 : a0;
            const int kst  = asel ? 0  : kst0;
            const int gof  = asel ? L0 : 0;
            const int L    = asel ? L1 : L0;
            if (lane < L) {
                dout[(size_t)s*OUT_SIDE + (size_t)(aa*NB + b)*KP1 + kst + lane]
                    = Tl[(gof + lane)*TLP + b];
            }
        }
    }
    if (tid == 0)
        sums[s*129 + rb] = (lsumd[0] + lsumd[1]) + (lsumd[2] + lsumd[3]);
}

// Finish: scale out by 1/Z per side; patch the 128 momentum-updated rows.
__global__ __launch_bounds__(256) void k_finish(
    const float* __restrict__ v1, const float* __restrict__ v2,
    const float* __restrict__ mem1, const float* __restrict__ mem2,
    const int* __restrict__ y,
    float* __restrict__ dout, const double* __restrict__ sums)
{
    const int bid = blockIdx.x;
    const int tid = threadIdx.x;

    if (bid < 32) {
        const int bank = bid >> 4;
        const int wave = tid >> 6;
        const int lane = tid & 63;
        const int b    = (bid & 15) * 4 + wave;
        const float* mem = bank ? mem2 : mem1;
        const float* v   = bank ? v2 : v1;
        float* nm = dout + (size_t)2*OUT_SIDE + (size_t)bank*NROWS*DD;

        const int row = y[b];
        bool skip = false;
        for (int b2 = b + 1; b2 < NB; ++b2) skip |= (y[b2] == row);  // last occurrence wins
        if (!skip) {
            const float2 m2 = *(const float2*)(mem + (size_t)row*DD + lane*2);
            const float2 w2 = *(const float2*)(v + (size_t)b*DD + lane*2);
            float px = 0.5f*(m2.x + w2.x);
            float py = 0.5f*(m2.y + w2.y);
            float ss = px*px + py*py;
            #pragma unroll
            for (int m = 1; m < 64; m <<= 1) ss += __shfl_xor(ss, m, 64);
            const float rn = 1.0f / sqrtf(ss);
            *(float2*)(nm + (size_t)row*DD + lane*2) = make_float2(px*rn, py*rn);
        }
    } else {
        __shared__ double fsh;
        const size_t i = (size_t)(bid - 32)*256 + tid;   // float4 index into out region
        const int side = (i >= (size_t)OUT_SIDE/4) ? 1 : 0;
        if (tid < 64) {
            double z = sums[side*129 + tid] + sums[side*129 + 64 + tid];
            if (tid == 0) z += sums[side*129 + 128];
            #pragma unroll
            for (int m = 1; m < 64; m <<= 1) z += __shfl_xor(z, m, 64);
            if (tid == 0) fsh = (double)OUT_SIDE / (z * (double)NROWS);
        }
        __syncthreads();
        const float f = (float)fsh;
        float4* io = (float4*)dout;
        float4 t = io[i];
        t.x *= f; t.y *= f; t.z *= f; t.w *= f;
        io[i] = t;
    }
}

extern "C" void kernel_launch(void* const* d_in, const int* in_sizes, int n_in,
                              void* d_out, int out_size, void* d_ws, size_t ws_size,
                              hipStream_t stream) {
    const float* v1   = (const float*)d_in[0];
    const float* v2   = (const float*)d_in[1];
    const float* mem1 = (const float*)d_in[2];
    const float* mem2 = (const float*)d_in[3];
    const int*   y    = (const int*)d_in[4];
    const int*   idx  = (const int*)d_in[5];
    float*  out  = (float*)d_out;
    double* sums = (double*)d_ws;

    k_copy<<<2*NF4PB, 256, 0, stream>>>(mem1, mem2, out);
    k_gemm<<<258, 256, 0, stream>>>(v1, v2, mem1, mem2, y, idx, out, sums);
    k_finish<<<32 + (2*OUT_SIDE/4)/256, 256, 0, stream>>>(v1, v2, mem1, mem2, y, out, sums);
}

// Round 11
// 32.005 us; speedup vs baseline: 1.5647x; 1.5647x over previous
//
#include <hip/hip_runtime.h>

#define NB 64
#define KP1 129
#define DD 128
#define NROWS 50000
#define EPSF 1e-6f
#define E128F (128.0f*EPSF*EPSF)
#define OUT_SIDE (NB*NB*KP1)            // 528384 per side
#define L2E_T 28.853900817779268f       // log2(e)/T, T=0.05
#define RSQRT_D 0.08838834764831845f    // 1/sqrt(128)
#define NGEMM (2*129)                   // 2 sides x 129 rowblocks of 64 w-rows
#define NCOPY 512

__device__ __forceinline__ float4 ldf4(const float* p) { return *(const float4*)p; }

// Champion structure (round 4): 258 gemm blocks dispatched FIRST (full-K
// staging, one barrier), 512 copy blocks behind them. Only deltas vs r4:
// per-block Z slots (no atomics, no memset node).
__global__ __launch_bounds__(256) void k_big(
    const float* __restrict__ v1, const float* __restrict__ v2,
    const float* __restrict__ mem1, const float* __restrict__ mem2,
    const int* __restrict__ y, const int* __restrict__ idx,
    float* __restrict__ dout, double* __restrict__ sums)
{
    const int bid = blockIdx.x;
    const int tid = threadIdx.x;

    if (bid < NGEMM) {
        __shared__ float Alds[128*64];        // [d][r] w-rows, transposed
        __shared__ float Blds[128*64];        // [d][c] anchor rows, transposed
        __shared__ float4 ared[64][4];        // (w·u, Sw, Sww, -) partials per (row, chunk)
        __shared__ float4 bred[64][4];        // (San, Sanan, an·u0, an·u1) per (col, chunk)
        __shared__ float2 sured[2][4];        // (Su, Suu) partials
        __shared__ float dotwul[64], swl[64], wql[64];
        __shared__ float sanl[64], anql[64], g1l0[64], g1l1[64];
        __shared__ int   lidxl[64], yl[64];
        __shared__ float sul[2], usql[2];
        __shared__ double zred[256];

        const int s  = bid / 129;             // side: 0 -> (v1, mem2), 1 -> (v2, mem1)
        const int rb = bid % 129;
        const float* v   = s ? v2 : v1;
        const float* mem = s ? mem1 : mem2;
        const int a0 = (rb*64) / 129;
        const int a1 = (rb*64 + 63) / 129;    // a0 or a0+1

        const int r  = tid & 63;
        const int ch = tid >> 6;              // 4 d-chunks of 32

        // ---- stage A: 64 w-rows (g = rb*64 + r), compute w·u[a(g)], Sw, Sww ----
        {
            const int g    = rb*64 + r;
            const int ag   = g / 129;
            const int mrow = idx[g];
            if (ch == 0) { lidxl[r] = mrow; yl[r] = y[r]; }
            const float* ap = mem + (size_t)mrow*DD + ch*32;
            const float* up = v + (size_t)ag*DD + ch*32;
            float pd = 0.f, ps = 0.f, pq = 0.f;
            #pragma unroll
            for (int i = 0; i < 8; ++i) {
                float4 w  = ldf4(ap + i*4);
                float4 uu = ldf4(up + i*4);
                const int d = ch*32 + i*4;
                Alds[(d+0)*64 + r] = w.x;
                Alds[(d+1)*64 + r] = w.y;
                Alds[(d+2)*64 + r] = w.z;
                Alds[(d+3)*64 + r] = w.w;
                pd = fmaf(w.x,uu.x, fmaf(w.y,uu.y, fmaf(w.z,uu.z, fmaf(w.w,uu.w, pd))));
                ps += (w.x + w.y) + (w.z + w.w);
                pq = fmaf(w.x,w.x, fmaf(w.y,w.y, fmaf(w.z,w.z, fmaf(w.w,w.w, pq))));
            }
            ared[r][ch] = make_float4(pd, ps, pq, 0.f);
        }
        // ---- stage B: 64 anchor cols, compute San, ||an||^2, an·u[a0], an·u[a1] ----
        {
            const int c = r;
            const int arow = y[c];
            const float* bp  = mem + (size_t)arow*DD + ch*32;
            const float* u0p = v + (size_t)a0*DD + ch*32;
            const float* u1p = v + (size_t)a1*DD + ch*32;
            float pn = 0.f, pq = 0.f, p0 = 0.f, p1 = 0.f;
            #pragma unroll
            for (int i = 0; i < 8; ++i) {
                float4 an4 = ldf4(bp  + i*4);
                float4 u0  = ldf4(u0p + i*4);
                float4 u1  = ldf4(u1p + i*4);
                const int d = ch*32 + i*4;
                Blds[(d+0)*64 + c] = an4.x;
                Blds[(d+1)*64 + c] = an4.y;
                Blds[(d+2)*64 + c] = an4.z;
                Blds[(d+3)*64 + c] = an4.w;
                pn += (an4.x + an4.y) + (an4.z + an4.w);
                pq = fmaf(an4.x,an4.x, fmaf(an4.y,an4.y, fmaf(an4.z,an4.z, fmaf(an4.w,an4.w, pq))));
                p0 = fmaf(an4.x,u0.x, fmaf(an4.y,u0.y, fmaf(an4.z,u0.z, fmaf(an4.w,u0.w, p0))));
                p1 = fmaf(an4.x,u1.x, fmaf(an4.y,u1.y, fmaf(an4.z,u1.z, fmaf(an4.w,u1.w, p1))));
            }
            bred[c][ch] = make_float4(pn, pq, p0, p1);
        }
        // ---- stage u stats: Su, ||u||^2 for a0, a1 ----
        if (tid < 8) {
            const int au = tid & 1, c2 = tid >> 1;
            const float* up = v + (size_t)(au ? a1 : a0)*DD + c2*32;
            float ps = 0.f, pq = 0.f;
            #pragma unroll
            for (int i = 0; i < 8; ++i) {
                float4 uu = ldf4(up + i*4);
                ps += (uu.x + uu.y) + (uu.z + uu.w);
                pq = fmaf(uu.x,uu.x, fmaf(uu.y,uu.y, fmaf(uu.z,uu.z, fmaf(uu.w,uu.w, pq))));
            }
            sured[au][c2] = make_float2(ps, pq);
        }
        __syncthreads();
        if (tid < 64) {
            float4 q0 = ared[tid][0], q1 = ared[tid][1], q2 = ared[tid][2], q3 = ared[tid][3];
            dotwul[tid] = (q0.x+q1.x)+(q2.x+q3.x);
            swl[tid]    = (q0.y+q1.y)+(q2.y+q3.y);
            wql[tid]    = (q0.z+q1.z)+(q2.z+q3.z);
        } else if (tid < 128) {
            const int c = tid - 64;
            float4 q0 = bred[c][0], q1 = bred[c][1], q2 = bred[c][2], q3 = bred[c][3];
            sanl[c] = (q0.x+q1.x)+(q2.x+q3.x);
            anql[c] = (q0.y+q1.y)+(q2.y+q3.y);
            g1l0[c] = (q0.z+q1.z)+(q2.z+q3.z);
            g1l1[c] = (q0.w+q1.w)+(q2.w+q3.w);
        } else if (tid < 130) {
            const int au = tid - 128;
            float2 e0 = sured[au][0], e1 = sured[au][1], e2 = sured[au][2], e3 = sured[au][3];
            sul[au]  = (e0.x+e1.x)+(e2.x+e3.x);
            usql[au] = (e0.y+e1.y)+(e2.y+e3.y);
        }
        __syncthreads();

        // ---- GEMM: C-tile 64x64, thread tile 4r x 4c ----
        const int r0 = (tid >> 4) << 2;
        const int c0 = (tid & 15) << 2;
        float acc[4][4] = {{0.f,0.f,0.f,0.f},{0.f,0.f,0.f,0.f},{0.f,0.f,0.f,0.f},{0.f,0.f,0.f,0.f}};
        #pragma unroll 8
        for (int k = 0; k < 128; ++k) {
            float4 av = *(float4*)&Alds[k*64 + r0];
            float4 bv = *(float4*)&Blds[k*64 + c0];
            acc[0][0]=fmaf(av.x,bv.x,acc[0][0]); acc[0][1]=fmaf(av.x,bv.y,acc[0][1]);
            acc[0][2]=fmaf(av.x,bv.z,acc[0][2]); acc[0][3]=fmaf(av.x,bv.w,acc[0][3]);
            acc[1][0]=fmaf(av.y,bv.x,acc[1][0]); acc[1][1]=fmaf(av.y,bv.y,acc[1][1]);
            acc[1][2]=fmaf(av.y,bv.z,acc[1][2]); acc[1][3]=fmaf(av.y,bv.w,acc[1][3]);
            acc[2][0]=fmaf(av.z,bv.x,acc[2][0]); acc[2][1]=fmaf(av.z,bv.y,acc[2][1]);
            acc[2][2]=fmaf(av.z,bv.z,acc[2][2]); acc[2][3]=fmaf(av.z,bv.w,acc[2][3]);
            acc[3][0]=fmaf(av.w,bv.x,acc[3][0]); acc[3][1]=fmaf(av.w,bv.y,acc[3][1]);
            acc[3][2]=fmaf(av.w,bv.z,acc[3][2]); acc[3][3]=fmaf(av.w,bv.w,acc[3][3]);
        }

        // ---- epilogue: assemble, exp, write out, Z-partials ----
        float dwr[4], swr[4], wqr[4];
        int   idr[4], aur[4];
        size_t obase[4];
        #pragma unroll
        for (int i = 0; i < 4; ++i) {
            const int rr = r0 + i, gg = rb*64 + rr;
            const int aa = gg / 129, kk = gg - aa*129;
            dwr[i] = dotwul[rr]; swr[i] = swl[rr]; wqr[i] = wql[rr];
            idr[i] = lidxl[rr];  aur[i] = aa - a0;
            obase[i] = (size_t)s*OUT_SIDE + (size_t)(aa*64)*129 + kk;
        }
        double zacc = 0.0;
        #pragma unroll
        for (int j = 0; j < 4; ++j) {
            const int b = c0 + j;
            const float sanb = sanl[b], anqb = anql[b];
            const int yb = yl[b];
            const float g1v[2] = { g1l0[b], g1l1[b] };
            float rdu[2], vem[2];
            #pragma unroll
            for (int au = 0; au < 2; ++au) {
                const float du2 = usql[au] - 2.f*g1v[au] + anqb
                                + 2.f*EPSF*(sul[au] - sanb) + E128F;
                rdu[au] = rsqrtf(fmaxf(du2, 1e-20f));
                vem[au] = exp2f((sul[au] - sanb + 128.f*EPSF) * rdu[au] * (RSQRT_D*L2E_T));
            }
            #pragma unroll
            for (int i = 0; i < 4; ++i) {
                const int au = aur[i];
                const float C2 = acc[i][j];
                const float N = dwr[i] - C2 - g1v[au] + anqb
                              + EPSF*(swr[i] + sul[au] - 2.f*sanb) + E128F;
                const float dw2 = wqr[i] - 2.f*C2 + anqb
                                + 2.f*EPSF*(swr[i] - sanb) + E128F;
                float val = exp2f(N * rsqrtf(fmaxf(dw2, 1e-20f)) * rdu[au] * L2E_T);
                if (idr[i] == yb) val = vem[au];
                dout[obase[i] + (size_t)b*129] = val;
                zacc += (double)val;
            }
        }
        zred[tid] = zacc;
        __syncthreads();
        if (tid < 64) {
            double z = (zred[tid] + zred[tid+64]) + (zred[tid+128] + zred[tid+192]);
            #pragma unroll
            for (int m = 1; m < 64; m <<= 1) z += __shfl_xor(z, m, 64);
            if (tid == 0) sums[s*129 + rb] = z;   // per-block slot, no atomics
        }
    } else {
        // ---------------- bank copy role ----------------
        float* nm1 = dout + (size_t)2*OUT_SIDE;
        float* nm2 = nm1 + (size_t)NROWS*DD;
        const int cid = bid - NGEMM;                  // 0..511
        const size_t nf4 = (size_t)NROWS*DD/4;        // 1,600,000 per bank
        const float4* s1 = (const float4*)mem1;
        const float4* s2 = (const float4*)mem2;
        float4* d1 = (float4*)nm1;
        float4* d2 = (float4*)nm2;
        #pragma unroll 2
        for (size_t i = (size_t)cid*256 + tid; i < nf4; i += (size_t)NCOPY*256) {
            d1[i] = s1[i];
            d2[i] = s2[i];
        }
    }
}

// Finish: scale out by 1/Z per side; patch the 128 momentum-updated rows.
__global__ __launch_bounds__(256) void k_finish(
    const float* __restrict__ v1, const float* __restrict__ v2,
    const float* __restrict__ mem1, const float* __restrict__ mem2,
    const int* __restrict__ y,
    float* __restrict__ dout, const double* __restrict__ sums)
{
    const int bid = blockIdx.x;
    const int tid = threadIdx.x;

    if (bid < 32) {
        const int bank = bid >> 4;
        const int wave = tid >> 6;
        const int lane = tid & 63;
        const int b    = (bid & 15) * 4 + wave;
        const float* mem = bank ? mem2 : mem1;
        const float* v   = bank ? v2 : v1;
        float* nm = dout + (size_t)2*OUT_SIDE + (size_t)bank*NROWS*DD;

        const int row = y[b];
        bool skip = false;
        for (int b2 = b + 1; b2 < NB; ++b2) skip |= (y[b2] == row);  // last occurrence wins
        if (!skip) {
            const float2 m2 = *(const float2*)(mem + (size_t)row*DD + lane*2);
            const float2 w2 = *(const float2*)(v + (size_t)b*DD + lane*2);
            float px = 0.5f*(m2.x + w2.x);
            float py = 0.5f*(m2.y + w2.y);
            float ss = px*px + py*py;
            #pragma unroll
            for (int m = 1; m < 64; m <<= 1) ss += __shfl_xor(ss, m, 64);
            const float rn = 1.0f / sqrtf(ss);
            *(float2*)(nm + (size_t)row*DD + lane*2) = make_float2(px*rn, py*rn);
        }
    } else {
        __shared__ double fsh;
        const size_t i = (size_t)(bid - 32)*256 + tid;   // float4 index into out region
        const int side = (i >= (size_t)OUT_SIDE/4) ? 1 : 0;
        // wave 0 reduces this side's 129 per-block Z partials, broadcasts via LDS
        if (tid < 64) {
            double z = sums[side*129 + tid] + sums[side*129 + 64 + tid];
            if (tid == 0) z += sums[side*129 + 128];
            #pragma unroll
            for (int m = 1; m < 64; m <<= 1) z += __shfl_xor(z, m, 64);
            if (tid == 0) fsh = (double)OUT_SIDE / (z * (double)NROWS);
        }
        __syncthreads();
        const float f = (float)fsh;
        float4* io = (float4*)dout;
        float4 t = io[i];
        t.x *= f; t.y *= f; t.z *= f; t.w *= f;
        io[i] = t;
    }
}

extern "C" void kernel_launch(void* const* d_in, const int* in_sizes, int n_in,
                              void* d_out, int out_size, void* d_ws, size_t ws_size,
                              hipStream_t stream) {
    const float* v1   = (const float*)d_in[0];
    const float* v2   = (const float*)d_in[1];
    const float* mem1 = (const float*)d_in[2];
    const float* mem2 = (const float*)d_in[3];
    const int*   y    = (const int*)d_in[4];
    const int*   idx  = (const int*)d_in[5];
    float*  out  = (float*)d_out;
    double* sums = (double*)d_ws;

    k_big<<<NGEMM + NCOPY, 256, 0, stream>>>(v1, v2, mem1, mem2, y, idx, out, sums);
    k_finish<<<32 + (2*OUT_SIDE/4)/256, 256, 0, stream>>>(v1, v2, mem1, mem2, y, out, sums);
}